// Round 5
// baseline (191.534 us; speedup 1.0000x reference)
//
#include <hip/hip_runtime.h>

// Edge (replicate) pad, width 2 on H and W.
// In:  (32, 256, 56, 56) fp32  -> NC = 8192 planes of 56x56
// Out: (32, 256, 60, 60) fp32
//
// v4 (2nd resubmit; two prior attempts died to container-infra failures
// before compile): ILP-2 — each thread processes the SAME (nc%4096, oh, w4)
// position in TWO planes (nc and nc+4096). Two independent loads issue
// back-to-back (2 outstanding vmcnt per thread), two independent NT stores;
// all index math amortized over 32 B moved.
// 3,686,400 threads = 14,400 blocks exact.
//
// Load scheme (measured-neutral vs aligned+DPP in v2, so keep the simpler
// one): one dwordx4 at a clamped window base, edge cases fixed up with
// register cndmasks only — no loads under divergent control flow.
//   w4=0 : base=0,  window {s0..s3},   out {s0,s0,s0,s1}
//   w4=14: base=52, window {s52..s55}, out {s54,s55,s55,s55}
//   else : base=ow0-2, identity

#define IN_H  56
#define IN_W  56
#define OUT_H 60
#define OUT_W 60
#define PAD   2
#define W4       (OUT_W / 4)          // 15 float4 per output row
#define IN_PLANE (IN_H * IN_W)        // 3136 floats
#define OUT_P4   (OUT_H * W4)         // 900 float4 per plane
#define NCH      4096                 // half of the 8192 planes

typedef float f4u __attribute__((ext_vector_type(4), aligned(4)));
typedef float f4a __attribute__((ext_vector_type(4), aligned(16)));

__device__ __forceinline__ f4a edge_fix(f4u u, int w4) {
    f4a v;
    v.x = (w4 == W4 - 1) ? u.z : u.x;
    v.y = (w4 == 0)      ? u.x : ((w4 == W4 - 1) ? u.w : u.y);
    v.z = (w4 == 0)      ? u.x : ((w4 == W4 - 1) ? u.w : u.z);
    v.w = (w4 == 0)      ? u.y : ((w4 == W4 - 1) ? u.w : u.w);
    return v;
}

__global__ __launch_bounds__(256) void pad2d_edge_kernel(
    const float* __restrict__ in, float* __restrict__ out, int n_half) {
    int idx = blockIdx.x * blockDim.x + threadIdx.x;
    if (idx >= n_half) return;        // grid is exact; guard is free

    int w4 = idx % W4;
    int t  = idx / W4;                // nc*OUT_H + oh, nc in [0,4096)
    int oh = t % OUT_H;
    int nc = t / OUT_H;

    int ih = min(max(oh - PAD, 0), IN_H - 1);
    const float* src = in + (size_t)nc * IN_PLANE + (size_t)ih * IN_W;

    int ow0  = w4 * 4;
    int base = min(max(ow0 - PAD, 0), IN_W - 4);   // 0..52, always in-bounds

    // Two independent loads: plane nc and plane nc+4096 (same offsets).
    f4u u0 = *reinterpret_cast<const f4u*>(src + base);
    f4u u1 = *reinterpret_cast<const f4u*>(src + (size_t)NCH * IN_PLANE + base);

    f4a v0 = edge_fix(u0, w4);
    f4a v1 = edge_fix(u1, w4);

    f4a* dst = reinterpret_cast<f4a*>(out);
    __builtin_nontemporal_store(v0, dst + idx);
    __builtin_nontemporal_store(v1, dst + idx + (size_t)NCH * OUT_P4);
}

extern "C" void kernel_launch(void* const* d_in, const int* in_sizes, int n_in,
                              void* d_out, int out_size, void* d_ws, size_t ws_size,
                              hipStream_t stream) {
    const float* x = (const float*)d_in[0];
    float* out = (float*)d_out;

    // out_size is in ELEMENTS: 32*256*60*60 = 29,491,200 floats.
    int n_half = out_size / 4 / 2;    // 3,686,400 float4 pairs
    int block = 256;
    int grid = (n_half + block - 1) / block;   // 14,400 exact
    pad2d_edge_kernel<<<grid, block, 0, stream>>>(x, out, n_half);
}